// Round 3
// baseline (1294.372 us; speedup 1.0000x reference)
//
#include <hip/hip_runtime.h>
#include <cmath>

namespace {
constexpr int B_  = 2;
constexpr int S_  = 1024;
constexpr int H_  = 512;
constexpr int NH_ = 8;
constexpr int HD_ = 64;
constexpr int I_  = 512;
constexpr int K_  = 65536;
constexpr int M_  = B_ * S_;   // 2048
constexpr int CAP = 1024;      // candidate slots per row
constexpr int NT_ = 8;         // n-tiles swept per sim block
constexpr float MARGIN = 0.15f;  // ~11 sigma of f16 dot error (sigma~0.013)
}

typedef __attribute__((ext_vector_type(8))) _Float16 half8;
typedef __attribute__((ext_vector_type(4))) float f32x4;

__device__ inline unsigned mono(float f) {
  unsigned u = __float_as_uint(f);
  return (u & 0x80000000u) ? ~u : (u | 0x80000000u);
}
__device__ inline float unmono(unsigned m) {
  unsigned u = (m & 0x80000000u) ? (m & 0x7fffffffu) : ~m;
  return __uint_as_float(u);
}

// ---------------------------------------------------------------------------
// fp32 GEMM (B-transposed) — used ONLY for idx = sigmoid(X . i_w^T).
// idx must be fp32-accurate: argmax top-2 gaps are O(2) with ~delta/2.2 tail,
// f16 idx (~2e-3 sim perturbation) would flip ~4 rows' choices -> fail.
// ---------------------------------------------------------------------------
__global__ __launch_bounds__(256) void bikv_gemm_f32_sig(
    const float* __restrict__ A, const float* __restrict__ W,
    float* __restrict__ C, int N, int Kd)
{
  __shared__ float As[64][17];
  __shared__ float Ws[64][17];
  const int t  = threadIdx.x;
  const int m0 = blockIdx.x * 64;
  const int n0 = blockIdx.y * 64;
  const int ty = t >> 4, tx = t & 15;
  const int lr = t >> 2, lc = (t & 3) << 2;
  const long arow = (long)(m0 + lr) * Kd;
  const long wrow = (long)(n0 + lr) * Kd;
  float acc[4][4] = {};
  for (int kk = 0; kk < Kd; kk += 16) {
    __syncthreads();
    const float4 av = *(const float4*)(A + arow + kk + lc);
    const float4 wv = *(const float4*)(W + wrow + kk + lc);
    As[lr][lc+0]=av.x; As[lr][lc+1]=av.y; As[lr][lc+2]=av.z; As[lr][lc+3]=av.w;
    Ws[lr][lc+0]=wv.x; Ws[lr][lc+1]=wv.y; Ws[lr][lc+2]=wv.z; Ws[lr][lc+3]=wv.w;
    __syncthreads();
#pragma unroll
    for (int c = 0; c < 16; ++c) {
      float a[4], b[4];
#pragma unroll
      for (int i = 0; i < 4; ++i) a[i] = As[ty + 16*i][c];
#pragma unroll
      for (int j = 0; j < 4; ++j) b[j] = Ws[tx + 16*j][c];
#pragma unroll
      for (int i = 0; i < 4; ++i)
#pragma unroll
        for (int j = 0; j < 4; ++j) acc[i][j] = fmaf(a[i], b[j], acc[i][j]);
    }
  }
#pragma unroll
  for (int i = 0; i < 4; ++i) {
    const long m = m0 + ty + 16*i;
#pragma unroll
    for (int j = 0; j < 4; ++j) {
      const int n = n0 + tx + 16*j;
      C[m * N + n] = 1.0f / (1.0f + expf(-acc[i][j]));
    }
  }
}

// ---------------------------------------------------------------------------
// f32 -> f16 conversion, 8 elems/thread
// ---------------------------------------------------------------------------
__global__ __launch_bounds__(256) void bikv_f2h(
    const float* __restrict__ src, _Float16* __restrict__ dst, int n8)
{
  const int i = blockIdx.x * 256 + threadIdx.x;
  if (i >= n8) return;
  const float4 x = *(const float4*)(src + (long)i * 8);
  const float4 y = *(const float4*)(src + (long)i * 8 + 4);
  half8 o;
  o[0]=(_Float16)x.x; o[1]=(_Float16)x.y; o[2]=(_Float16)x.z; o[3]=(_Float16)x.w;
  o[4]=(_Float16)y.x; o[5]=(_Float16)y.y; o[6]=(_Float16)y.z; o[7]=(_Float16)y.w;
  *(half8*)(dst + (long)i * 8) = o;
}

__global__ void bikv_zero(unsigned* a, int* cc) {
  const int i = blockIdx.x * 256 + threadIdx.x;
  if (i < M_) { a[i] = 0u; cc[i] = 0; }
}

// ---------------------------------------------------------------------------
// Gather chosen rows of keys_tab/values_tab and convert to f16.
// ---------------------------------------------------------------------------
__global__ __launch_bounds__(256) void bikv_gather_kv(
    const int* __restrict__ ch, const float* __restrict__ ktab,
    const float* __restrict__ vtab, _Float16* __restrict__ ck,
    _Float16* __restrict__ cv)
{
  const int i = blockIdx.x * 256 + threadIdx.x;   // i < M_*64
  const int m = i >> 6, c8 = (i & 63) * 8;
  const long src = (long)ch[m] * H_ + c8;
  const long dst = (long)m * H_ + c8;
  {
    const float4 a = *(const float4*)(ktab + src);
    const float4 b = *(const float4*)(ktab + src + 4);
    half8 o;
    o[0]=(_Float16)a.x; o[1]=(_Float16)a.y; o[2]=(_Float16)a.z; o[3]=(_Float16)a.w;
    o[4]=(_Float16)b.x; o[5]=(_Float16)b.y; o[6]=(_Float16)b.z; o[7]=(_Float16)b.w;
    *(half8*)(ck + dst) = o;
  }
  {
    const float4 a = *(const float4*)(vtab + src);
    const float4 b = *(const float4*)(vtab + src + 4);
    half8 o;
    o[0]=(_Float16)a.x; o[1]=(_Float16)a.y; o[2]=(_Float16)a.z; o[3]=(_Float16)a.w;
    o[4]=(_Float16)b.x; o[5]=(_Float16)b.y; o[6]=(_Float16)b.z; o[7]=(_Float16)b.w;
    *(half8*)(cv + dst) = o;
  }
}

// ---------------------------------------------------------------------------
// f16 MFMA GEMM, B-transposed: C[m,n] = act(sum_k A[row(m),k]*W[n,k]) (+bvec)
// 64x64 tile, 4 waves (2x2 of 32x32), 16x16x32_f16, global_load_lds staging.
// Optionally writes an f16 copy of C.
// ---------------------------------------------------------------------------
template<bool SIG, bool GATH, bool BVEC, bool WF16>
__global__ __launch_bounds__(256) void bikv_gemm_h(
    const _Float16* __restrict__ A, const _Float16* __restrict__ W,
    float* __restrict__ C, _Float16* __restrict__ C16,
    const int* __restrict__ gidx, const float* __restrict__ bvec,
    int N, int Kd, long sA, long sW, long sC)
{
  A += (long)blockIdx.z * sA;
  W += (long)blockIdx.z * sW;
  C += (long)blockIdx.z * sC;
  if (WF16) C16 += (long)blockIdx.z * sC;
  __shared__ _Float16 As[64 * 32];
  __shared__ _Float16 Ws[64 * 32];
  const int t = threadIdx.x;
  const int w = t >> 6, l = t & 63;
  const int q = l >> 4, c = l & 15;
  const int wm = w >> 1, wn = w & 1;
  const int m0 = blockIdx.x * 64;
  const int n0 = blockIdx.y * 64;
  const int srow = t >> 2, schunk = t & 3;
  const long abase = (long)(GATH ? gidx[m0 + srow] : (m0 + srow)) * Kd;
  const long wbase = (long)(n0 + srow) * Kd;
  const int lbase = w * 1024;          // bytes; wave-uniform LDS dest base

  f32x4 acc[2][2];
#pragma unroll
  for (int i = 0; i < 2; ++i)
#pragma unroll
    for (int j = 0; j < 2; ++j) acc[i][j] = (f32x4)0.0f;

  for (int kk = 0; kk < Kd; kk += 32) {
    __syncthreads();
    __builtin_amdgcn_global_load_lds(
        (const __attribute__((address_space(1))) void*)(A + abase + kk + schunk * 8),
        (__attribute__((address_space(3))) void*)((char*)As + lbase), 16, 0, 0);
    __builtin_amdgcn_global_load_lds(
        (const __attribute__((address_space(1))) void*)(W + wbase + kk + schunk * 8),
        (__attribute__((address_space(3))) void*)((char*)Ws + lbase), 16, 0, 0);
    __syncthreads();
    half8 af[2], bf[2];
#pragma unroll
    for (int i = 0; i < 2; ++i) {
      af[i] = *(const half8*)(As + (wm * 32 + i * 16 + c) * 32 + q * 8);
      bf[i] = *(const half8*)(Ws + (wn * 32 + i * 16 + c) * 32 + q * 8);
    }
#pragma unroll
    for (int i = 0; i < 2; ++i)
#pragma unroll
      for (int j = 0; j < 2; ++j)
        acc[i][j] = __builtin_amdgcn_mfma_f32_16x16x32_f16(af[i], bf[j], acc[i][j], 0, 0, 0);
  }
  // C/D layout: col = lane&15, row = (lane>>4)*4 + reg
#pragma unroll
  for (int i = 0; i < 2; ++i)
#pragma unroll
    for (int r = 0; r < 4; ++r) {
      const long m = m0 + wm * 32 + i * 16 + q * 4 + r;
#pragma unroll
      for (int j = 0; j < 2; ++j) {
        const int n = n0 + wn * 32 + j * 16 + c;
        float v = acc[i][j][r];
        if (BVEC) v += bvec[n];
        if (SIG)  v = 1.0f / (1.0f + expf(-v));
        C[m * N + n] = v;
        if (WF16) C16[m * N + n] = (_Float16)v;
      }
    }
}

// ---------------------------------------------------------------------------
// MFMA sim = idx . tab^T (f16 in, fp32 acc), fused approx-argmax + candidate
// collection. Persistent block sweeps NT_ n-tiles of 128 (amortizes epilogue
// 8x); grid.x = n-group so all 16 m-blocks of a tab slab land on one XCD
// (ids congruent mod 8) for L2 reuse. Epilogue is float-max only in the hot
// path; packing/atomics only behind the rare margin branch + at block end.
// ---------------------------------------------------------------------------
__global__ __launch_bounds__(256) void bikv_sim_mfma(
    const _Float16* __restrict__ A,    // idx f16 [M_, I_]
    const _Float16* __restrict__ Tb,   // tab f16 [K_, I_]
    unsigned* __restrict__ amaxU,
    int* __restrict__ ccount,
    unsigned long long* __restrict__ cand)
{
  __shared__ _Float16 As[128 * 32];
  __shared__ _Float16 Bs[128 * 32];
  const int t = threadIdx.x;
  const int w = t >> 6, l = t & 63;
  const int q = l >> 4, c = l & 15;
  const int wm = w >> 1, wn = w & 1;
  const int m0 = blockIdx.y * 128;
  const int nbase = blockIdx.x * (NT_ * 128);

  float known[4][4];
#pragma unroll
  for (int i = 0; i < 4; ++i)
#pragma unroll
    for (int r = 0; r < 4; ++r) known[i][r] = -INFINITY;

  for (int nt = 0; nt < NT_; ++nt) {
    const int n0 = nbase + nt * 128;
    f32x4 acc[4][4];
#pragma unroll
    for (int i = 0; i < 4; ++i)
#pragma unroll
      for (int j = 0; j < 4; ++j) acc[i][j] = (f32x4)0.0f;

    for (int kk = 0; kk < I_; kk += 32) {
      __syncthreads();
#pragma unroll
      for (int rep = 0; rep < 2; ++rep) {
        const int s   = rep * 256 + t;
        const int row = s >> 2, cp = s & 3;
        const long ga = (long)(m0 + row) * I_ + kk + cp * 8;
        const long gb = (long)(n0 + row) * I_ + kk + cp * 8;
        const int lbase = (rep * 256 + w * 64) * 16;   // bytes, wave-uniform
        __builtin_amdgcn_global_load_lds(
            (const __attribute__((address_space(1))) void*)(A + ga),
            (__attribute__((address_space(3))) void*)((char*)As + lbase), 16, 0, 0);
        __builtin_amdgcn_global_load_lds(
            (const __attribute__((address_space(1))) void*)(Tb + gb),
            (__attribute__((address_space(3))) void*)((char*)Bs + lbase), 16, 0, 0);
      }
      __syncthreads();
      half8 af[4], bf[4];
#pragma unroll
      for (int i = 0; i < 4; ++i) {
        af[i] = *(const half8*)(As + (wm * 64 + i * 16 + c) * 32 + q * 8);
        bf[i] = *(const half8*)(Bs + (wn * 64 + i * 16 + c) * 32 + q * 8);
      }
#pragma unroll
      for (int i = 0; i < 4; ++i)
#pragma unroll
        for (int j = 0; j < 4; ++j)
          acc[i][j] = __builtin_amdgcn_mfma_f32_16x16x32_f16(af[i], bf[j], acc[i][j], 0, 0, 0);
    }

    // epilogue for this n-tile: cheap float max path, rare candidate branch
#pragma unroll
    for (int i = 0; i < 4; ++i)
#pragma unroll
      for (int r = 0; r < 4; ++r) {
        float rowmax = fmaxf(fmaxf(acc[i][0][r], acc[i][1][r]),
                             fmaxf(acc[i][2][r], acc[i][3][r]));
#pragma unroll
        for (int off = 1; off < 16; off <<= 1)
          rowmax = fmaxf(rowmax, __shfl_xor(rowmax, off, 64));
        const float kv = known[i][r];
        if (rowmax > kv - MARGIN) {      // rare after the first tiles
          const float thr = fmaxf(kv, rowmax) - MARGIN;
          const int mrow = m0 + wm * 64 + i * 16 + q * 4 + r;
#pragma unroll
          for (int j = 0; j < 4; ++j) {
            const float v = acc[i][j][r];
            if (v > thr) {
              const unsigned col = (unsigned)(n0 + wn * 64 + j * 16 + c);
              const int pos = atomicAdd(&ccount[mrow], 1);
              if (pos < CAP)
                cand[(long)mrow * CAP + pos] =
                    ((unsigned long long)mono(v) << 32) |
                    (unsigned long long)(0xFFFFFFFFu - col);
            }
          }
        }
        known[i][r] = fmaxf(kv, rowmax);
      }
  }
  // single global max update per row per block
#pragma unroll
  for (int i = 0; i < 4; ++i)
#pragma unroll
    for (int r = 0; r < 4; ++r)
      if (c == 0) {
        const int mrow = m0 + wm * 64 + i * 16 + q * 4 + r;
        atomicMax(&amaxU[mrow], mono(known[i][r]));
      }
}

// ---------------------------------------------------------------------------
// Exact fp32 rescore of candidates within MARGIN of the final approx max.
// ---------------------------------------------------------------------------
__global__ __launch_bounds__(256) void bikv_rescore(
    const float* __restrict__ idxb, const float* __restrict__ tab,
    const unsigned* __restrict__ amaxU,
    const int* __restrict__ ccount, const unsigned long long* __restrict__ cand,
    int* __restrict__ ch)
{
  const int t = threadIdx.x, wv = t >> 6, l = t & 63;
  const int m = blockIdx.x * 4 + wv;
  float a[8];
  {
    const float4 a0 = *(const float4*)(idxb + (long)m * I_ + l * 8);
    const float4 a1 = *(const float4*)(idxb + (long)m * I_ + l * 8 + 4);
    a[0]=a0.x; a[1]=a0.y; a[2]=a0.z; a[3]=a0.w;
    a[4]=a1.x; a[5]=a1.y; a[6]=a1.z; a[7]=a1.w;
  }
  const int count = min(ccount[m], CAP);
  const float thrv = unmono(amaxU[m]) - MARGIN;
  unsigned long long best = 0ull;
  for (int cix = 0; cix < count; ++cix) {
    const unsigned long long p = cand[(long)m * CAP + cix];
    if (unmono((unsigned)(p >> 32)) <= thrv) continue;
    const unsigned col = 0xFFFFFFFFu - (unsigned)(p & 0xFFFFFFFFull);
    const float* tr = tab + (long)col * I_ + l * 8;
    float s = 0.f;
#pragma unroll
    for (int j = 0; j < 8; ++j) s = fmaf(a[j], tr[j], s);
#pragma unroll
    for (int off = 32; off >= 1; off >>= 1) s += __shfl_xor(s, off, 64);
    const unsigned long long pe =
        ((unsigned long long)mono(s) << 32) | (unsigned long long)(0xFFFFFFFFu - col);
    best = best > pe ? best : pe;
  }
  if (l == 0) ch[m] = (int)(0xFFFFFFFFu - (unsigned)(best & 0xFFFFFFFFull));
}

// ---------------------------------------------------------------------------
// Rotary (cos/sin indexed by HEAD index — reference quirk)
// ---------------------------------------------------------------------------
__global__ __launch_bounds__(256) void bikv_rotary(float* __restrict__ buf) {
  const int e  = blockIdx.x * 256 + threadIdx.x;
  const int j  = e & 31;
  const int nh = (e >> 5) & 7;
  const long m = e >> 8;
  const float inv = expf(-(float)j * (9.2103403719761836f / 32.0f));
  const float arg = (float)nh * inv;
  const float c = cosf(arg), s = sinf(arg);
  float* p = buf + m * H_ + nh * HD_ + j;
  const float x1 = p[0], x2 = p[32];
  p[0]  = x1 * c - x2 * s;
  p[32] = x2 * c + x1 * s;
}

// ---------------------------------------------------------------------------
// Flash attention, one wave per query. K tile row-major (b128 reads), V tile
// TRANSPOSED in LDS so the PV loop is b128 too. q/w read via uniform b128
// broadcasts. Writes o as f16 for the out-projection GEMM.
// ---------------------------------------------------------------------------
__global__ __launch_bounds__(256) void bikv_attn(
    const float* __restrict__ qb, const float* __restrict__ kb,
    const float* __restrict__ vb, const float* __restrict__ bias,
    _Float16* __restrict__ o16)
{
  const int b = blockIdx.z, h = blockIdx.y;
  const int t = threadIdx.x, wv = t >> 6, lane = t & 63;
  const int q = blockIdx.x * 4 + wv;
  __shared__ float kt[64][68];    // [key][d], stride 68: 16B-aligned rows, 2-way banks
  __shared__ float vt[64][68];    // [d][key] (transposed!)
  __shared__ float qs[4][64];
  __shared__ float wsh[4][64];
  const long qoff = (((long)(b * S_ + q)) * NH_ + h) * HD_;
  qs[wv][lane] = qb[qoff + lane];
  const float* biasrow = bias + ((long)b * S_ + q) * S_;
  const int ntiles = (blockIdx.x >> 4) + 1;
  float m = -INFINITY, l = 0.f, oacc = 0.f;
  for (int tau = 0; tau < ntiles; ++tau) {
    const int t0 = tau * 64;
    __syncthreads();
    {
      const float* ksrc = kb + (((long)(b * S_ + t0)) * NH_ + h) * HD_;
      const float* vsrc = vb + (((long)(b * S_ + t0)) * NH_ + h) * HD_;
      int l4 = t;
#pragma unroll
      for (int rep = 0; rep < 4; ++rep, l4 += 256) {
        const int row = l4 >> 4;
        const int c4  = (l4 & 15) << 2;
        const float4 k4 = *(const float4*)(ksrc + (long)row * (NH_*HD_) + c4);
        const float4 v4 = *(const float4*)(vsrc + (long)row * (NH_*HD_) + c4);
        *(float4*)&kt[row][c4] = k4;
        vt[c4+0][row] = v4.x; vt[c4+1][row] = v4.y;
        vt[c4+2][row] = v4.z; vt[c4+3][row] = v4.w;
      }
    }
    __syncthreads();
    const int tg = t0 + lane;
    const bool valid = tg <= q;
    float dot = 0.f;
#pragma unroll
    for (int d0 = 0; d0 < 16; ++d0) {
      const float4 k4 = *(const float4*)&kt[lane][d0 * 4];
      const float4 q4 = *(const float4*)&qs[wv][d0 * 4];   // uniform -> broadcast
      dot = fmaf(k4.x, q4.x, dot); dot = fmaf(k4.y, q4.y, dot);
      dot = fmaf(k4.z, q4.z, dot); dot = fmaf(k4.w, q4.w, dot);
    }
    const float sc = valid ? (dot * 0.125f + biasrow[tg]) : -INFINITY;
    float tm = sc;
#pragma unroll
    for (int off = 32; off >= 1; off >>= 1) tm = fmaxf(tm, __shfl_xor(tm, off, 64));
    const float mnew  = fmaxf(m, tm);
    const float alpha = expf(m - mnew);
    const float wgt = valid ? expf(sc - mnew) : 0.f;
    float sw = wgt;
#pragma unroll
    for (int off = 32; off >= 1; off >>= 1) sw += __shfl_xor(sw, off, 64);
    l = l * alpha + sw;
    wsh[wv][lane] = wgt;            // same-wave producer/consumer: no barrier
    float pa = 0.f;
#pragma unroll
    for (int tt0 = 0; tt0 < 16; ++tt0) {
      const float4 v4 = *(const float4*)&vt[lane][tt0 * 4];
      const float4 w4 = *(const float4*)&wsh[wv][tt0 * 4]; // uniform -> broadcast
      pa = fmaf(v4.x, w4.x, pa); pa = fmaf(v4.y, w4.y, pa);
      pa = fmaf(v4.z, w4.z, pa); pa = fmaf(v4.w, w4.w, pa);
    }
    oacc = oacc * alpha + pa;
    m = mnew;
  }
  o16[qoff + lane] = (_Float16)(oacc / l);
}

// ---------------------------------------------------------------------------
extern "C" void kernel_launch(void* const* d_in, const int* in_sizes, int n_in,
                              void* d_out, int out_size, void* d_ws, size_t ws_size,
                              hipStream_t stream)
{
  const float* X     = (const float*)d_in[0];
  const float* i_w   = (const float*)d_in[1];
  const float* q_w   = (const float*)d_in[2];
  const float* k_w   = (const float*)d_in[3];
  const float* v_w   = (const float*)d_in[4];
  const float* out_w = (const float*)d_in[5];
  const float* out_b = (const float*)d_in[6];
  const float* tab   = (const float*)d_in[7];
  const float* ktab  = (const float*)d_in[8];
  const float* vtab  = (const float*)d_in[9];
  float* out = (float*)d_out;

  char* ws = (char*)d_ws;
  size_t off = 0;
  auto alloc = [&](size_t bytes) -> void* {
    void* p = ws + off; off += (bytes + 255) & ~(size_t)255; return p;
  };
  auto amaxU   = (unsigned*)alloc(M_ * 4);
  auto ccount  = (int*)alloc(M_ * 4);
  auto choices = (int*)alloc(M_ * 4);
  auto idxb    = (float*)alloc((size_t)M_ * I_ * 4);
  auto chosenb = (float*)alloc((size_t)M_ * I_ * 4);     // f32 dummy out
  auto qbuf    = (float*)alloc((size_t)M_ * H_ * 4);
  auto kbuf    = (float*)alloc((size_t)M_ * H_ * 4);
  auto vbuf    = (float*)alloc((size_t)M_ * H_ * 4);
  auto biasb   = (float*)alloc((size_t)B_ * S_ * S_ * 4);
  auto idx16   = (_Float16*)alloc((size_t)M_ * I_ * 2);
  auto chosen16= (_Float16*)alloc((size_t)M_ * I_ * 2);
  auto X16     = (_Float16*)alloc((size_t)M_ * H_ * 2);
  auto iw16    = (_Float16*)alloc((size_t)H_ * H_ * 2);
  auto qw16    = (_Float16*)alloc((size_t)H_ * H_ * 2);
  auto kw16    = (_Float16*)alloc((size_t)H_ * H_ * 2);
  auto vw16    = (_Float16*)alloc((size_t)H_ * H_ * 2);
  auto ow16    = (_Float16*)alloc((size_t)H_ * H_ * 2);
  auto ck16    = (_Float16*)alloc((size_t)M_ * H_ * 2);
  auto cv16    = (_Float16*)alloc((size_t)M_ * H_ * 2);
  auto o16     = (_Float16*)alloc((size_t)M_ * H_ * 2);
  auto tab16   = (_Float16*)alloc((size_t)K_ * I_ * 2);   // 67 MB
  auto cand    = (unsigned long long*)alloc((size_t)M_ * CAP * 8);

  bikv_zero<<<M_/256, 256, 0, stream>>>(amaxU, ccount);

  // conversions
  bikv_f2h<<<(K_*I_/8)/256, 256, 0, stream>>>(tab, tab16, K_*I_/8);
  bikv_f2h<<<(M_*H_/8)/256, 256, 0, stream>>>(X, X16, M_*H_/8);
  bikv_f2h<<<(H_*H_/8)/256, 256, 0, stream>>>(i_w, iw16, H_*H_/8);
  bikv_f2h<<<(H_*H_/8)/256, 256, 0, stream>>>(q_w, qw16, H_*H_/8);
  bikv_f2h<<<(H_*H_/8)/256, 256, 0, stream>>>(k_w, kw16, H_*H_/8);
  bikv_f2h<<<(H_*H_/8)/256, 256, 0, stream>>>(v_w, vw16, H_*H_/8);
  bikv_f2h<<<(H_*H_/8)/256, 256, 0, stream>>>(out_w, ow16, H_*H_/8);

  // idx = sigmoid(X . i_w^T) — fp32 (argmax sensitivity), then f16 copy
  bikv_gemm_f32_sig<<<dim3(M_/64, I_/64), 256, 0, stream>>>(X, i_w, idxb, I_, H_);
  bikv_f2h<<<(M_*I_/8)/256, 256, 0, stream>>>(idxb, idx16, M_*I_/8);

  // MFMA sim + approx argmax + candidates; exact fp32 rescore
  bikv_sim_mfma<<<dim3(K_/(NT_*128), M_/128), 256, 0, stream>>>(
      idx16, tab16, amaxU, ccount, cand);
  bikv_rescore<<<M_/4, 256, 0, stream>>>(idxb, tab, amaxU, ccount, cand, choices);

  // gather chosen k/v rows -> f16
  bikv_gather_kv<<<(M_*64)/256, 256, 0, stream>>>(choices, ktab, vtab, ck16, cv16);

  // chosen = sigmoid(tab[choices] . i_w^T) — f16 ok (feeds bias only)
  bikv_gemm_h<true,true,false,true><<<dim3(M_/64, I_/64), 256, 0, stream>>>(
      tab16, iw16, chosenb, chosen16, choices, nullptr, I_, I_, 0, 0, 0);

  // q/k/v projections (f16 MFMA, f32 out for rotary/attn)
  bikv_gemm_h<false,false,false,false><<<dim3(M_/64, H_/64), 256, 0, stream>>>(
      X16, qw16, qbuf, nullptr, nullptr, nullptr, H_, H_, 0, 0, 0);
  bikv_gemm_h<false,false,false,false><<<dim3(M_/64, H_/64), 256, 0, stream>>>(
      ck16, kw16, kbuf, nullptr, nullptr, nullptr, H_, H_, 0, 0, 0);
  bikv_gemm_h<false,false,false,false><<<dim3(M_/64, H_/64), 256, 0, stream>>>(
      cv16, vw16, vbuf, nullptr, nullptr, nullptr, H_, H_, 0, 0, 0);

  bikv_rotary<<<(M_*NH_*32)/256, 256, 0, stream>>>(qbuf);
  bikv_rotary<<<(M_*NH_*32)/256, 256, 0, stream>>>(kbuf);

  // bias[b,s,t] = idx[b,s,:] . chosen[b,t,:]
  bikv_gemm_h<false,false,false,false><<<dim3(S_/64, S_/64, B_), 256, 0, stream>>>(
      idx16, chosen16, biasb, nullptr, nullptr, nullptr, S_, I_,
      (long)S_ * I_, (long)S_ * I_, (long)S_ * S_);

  bikv_attn<<<dim3(S_/4, NH_, B_), 256, 0, stream>>>(qbuf, kbuf, vbuf, biasb, o16);

  // out = o . out_w^T + out_b
  bikv_gemm_h<false,false,true,false><<<dim3(M_/64, H_/64), 256, 0, stream>>>(
      o16, ow16, out, nullptr, nullptr, out_b, H_, H_, 0, 0, 0);
}

// Round 4
// 850.954 us; speedup vs baseline: 1.5211x; 1.5211x over previous
//
#include <hip/hip_runtime.h>
#include <cmath>

namespace {
constexpr int B_  = 2;
constexpr int S_  = 1024;
constexpr int H_  = 512;
constexpr int NH_ = 8;
constexpr int HD_ = 64;
constexpr int I_  = 512;
constexpr int K_  = 65536;
constexpr int M_  = B_ * S_;    // 2048
constexpr int NB_ = K_ / 64;    // 1024 col-blocks per row in bm table
constexpr float MARGIN = 0.25f; // ~9.6 sigma of f16 dot error (sigma~0.013)
}

typedef __attribute__((ext_vector_type(8))) _Float16 half8;
typedef __attribute__((ext_vector_type(4))) float f32x4;

__device__ inline unsigned mono(float f) {
  unsigned u = __float_as_uint(f);
  return (u & 0x80000000u) ? ~u : (u | 0x80000000u);
}
__device__ inline float unmono(unsigned m) {
  unsigned u = (m & 0x80000000u) ? (m & 0x7fffffffu) : ~m;
  return __uint_as_float(u);
}

// ---------------------------------------------------------------------------
// fp32 GEMM (B-transposed) for idx = sigmoid(X . i_w^T); also emits f16 copy.
// idx must be fp32-accurate (argmax sensitivity); rescore uses the f32 copy.
// ---------------------------------------------------------------------------
__global__ __launch_bounds__(256) void bikv_gemm_f32_sig(
    const float* __restrict__ A, const float* __restrict__ W,
    float* __restrict__ C, _Float16* __restrict__ C16, int N, int Kd)
{
  __shared__ float As[64][17];
  __shared__ float Ws[64][17];
  const int t  = threadIdx.x;
  const int m0 = blockIdx.x * 64;
  const int n0 = blockIdx.y * 64;
  const int ty = t >> 4, tx = t & 15;
  const int lr = t >> 2, lc = (t & 3) << 2;
  const long arow = (long)(m0 + lr) * Kd;
  const long wrow = (long)(n0 + lr) * Kd;
  float acc[4][4] = {};
  for (int kk = 0; kk < Kd; kk += 16) {
    __syncthreads();
    const float4 av = *(const float4*)(A + arow + kk + lc);
    const float4 wv = *(const float4*)(W + wrow + kk + lc);
    As[lr][lc+0]=av.x; As[lr][lc+1]=av.y; As[lr][lc+2]=av.z; As[lr][lc+3]=av.w;
    Ws[lr][lc+0]=wv.x; Ws[lr][lc+1]=wv.y; Ws[lr][lc+2]=wv.z; Ws[lr][lc+3]=wv.w;
    __syncthreads();
#pragma unroll
    for (int c = 0; c < 16; ++c) {
      float a[4], b[4];
#pragma unroll
      for (int i = 0; i < 4; ++i) a[i] = As[ty + 16*i][c];
#pragma unroll
      for (int j = 0; j < 4; ++j) b[j] = Ws[tx + 16*j][c];
#pragma unroll
      for (int i = 0; i < 4; ++i)
#pragma unroll
        for (int j = 0; j < 4; ++j) acc[i][j] = fmaf(a[i], b[j], acc[i][j]);
    }
  }
#pragma unroll
  for (int i = 0; i < 4; ++i) {
    const long m = m0 + ty + 16*i;
#pragma unroll
    for (int j = 0; j < 4; ++j) {
      const int n = n0 + tx + 16*j;
      const float v = 1.0f / (1.0f + expf(-acc[i][j]));
      C[m * N + n] = v;
      C16[m * N + n] = (_Float16)v;
    }
  }
}

// ---------------------------------------------------------------------------
// f32 -> f16, 8 elems/thread (big buffers: tab)
// ---------------------------------------------------------------------------
__global__ __launch_bounds__(256) void bikv_f2h(
    const float* __restrict__ src, _Float16* __restrict__ dst, int n8)
{
  const int i = blockIdx.x * 256 + threadIdx.x;
  if (i >= n8) return;
  const float4 x = *(const float4*)(src + (long)i * 8);
  const float4 y = *(const float4*)(src + (long)i * 8 + 4);
  half8 o;
  o[0]=(_Float16)x.x; o[1]=(_Float16)x.y; o[2]=(_Float16)x.z; o[3]=(_Float16)x.w;
  o[4]=(_Float16)y.x; o[5]=(_Float16)y.y; o[6]=(_Float16)y.z; o[7]=(_Float16)y.w;
  *(half8*)(dst + (long)i * 8) = o;
}

// ---------------------------------------------------------------------------
// Fused f32->f16 for X + 5 weight matrices (one dispatch).
// Layout: [0,131072) -> X (1M elems /8); then 5 x 32768 chunks of 8.
// ---------------------------------------------------------------------------
__global__ __launch_bounds__(256) void bikv_f2h_multi(
    const float* __restrict__ X,   _Float16* __restrict__ X16,
    const float* __restrict__ w0,  _Float16* __restrict__ d0,
    const float* __restrict__ w1,  _Float16* __restrict__ d1,
    const float* __restrict__ w2,  _Float16* __restrict__ d2,
    const float* __restrict__ w3,  _Float16* __restrict__ d3,
    const float* __restrict__ w4,  _Float16* __restrict__ d4)
{
  const int i = blockIdx.x * 256 + threadIdx.x;   // < 294912
  const float* src; _Float16* dst; long rel;
  if (i < 131072) { src = X; dst = X16; rel = i; }
  else {
    const int j = i - 131072;
    const int w = j >> 15;
    rel = j & 32767;
    switch (w) {
      case 0: src = w0; dst = d0; break;
      case 1: src = w1; dst = d1; break;
      case 2: src = w2; dst = d2; break;
      case 3: src = w3; dst = d3; break;
      default: src = w4; dst = d4; break;
    }
  }
  const float4 x = *(const float4*)(src + rel * 8);
  const float4 y = *(const float4*)(src + rel * 8 + 4);
  half8 o;
  o[0]=(_Float16)x.x; o[1]=(_Float16)x.y; o[2]=(_Float16)x.z; o[3]=(_Float16)x.w;
  o[4]=(_Float16)y.x; o[5]=(_Float16)y.y; o[6]=(_Float16)y.z; o[7]=(_Float16)y.w;
  *(half8*)(dst + rel * 8) = o;
}

// ---------------------------------------------------------------------------
// Phase 1: sim = idx . tab^T (f16 MFMA, fp32 acc). For each (row, 64-colblock)
// write packed (mono(blockmax)<<32)|(63-argrel) to bm — deterministic, no
// atomics, no candidate lists. 128x128 tile, 4 waves (2x2 of 64x64), BK=64.
// ---------------------------------------------------------------------------
__global__ __launch_bounds__(256) void bikv_sim_bm(
    const _Float16* __restrict__ A,    // idx f16 [M_, I_]
    const _Float16* __restrict__ Tb,   // tab f16 [K_, I_]
    unsigned long long* __restrict__ bm)
{
  __shared__ _Float16 As[128 * 64];
  __shared__ _Float16 Bs[128 * 64];
  const int t = threadIdx.x;
  const int w = t >> 6, l = t & 63;
  const int q = l >> 4, c = l & 15;
  const int wm = w >> 1, wn = w & 1;
  const int m0 = blockIdx.x * 128;
  const int n0 = blockIdx.y * 128;

  f32x4 acc[4][4];
#pragma unroll
  for (int i = 0; i < 4; ++i)
#pragma unroll
    for (int j = 0; j < 4; ++j) acc[i][j] = (f32x4)0.0f;

  for (int kk = 0; kk < I_; kk += 64) {
    __syncthreads();
#pragma unroll
    for (int rep = 0; rep < 4; ++rep) {
      const int s   = rep * 256 + t;
      const int row = s >> 3, cp = s & 7;          // 8 x 16B chunks per 64-f16 row
      const long ga = (long)(m0 + row) * I_ + kk + cp * 8;
      const long gb = (long)(n0 + row) * I_ + kk + cp * 8;
      const int lbase = (rep * 256 + w * 64) * 16; // bytes, wave-uniform
      __builtin_amdgcn_global_load_lds(
          (const __attribute__((address_space(1))) void*)(A + ga),
          (__attribute__((address_space(3))) void*)((char*)As + lbase), 16, 0, 0);
      __builtin_amdgcn_global_load_lds(
          (const __attribute__((address_space(1))) void*)(Tb + gb),
          (__attribute__((address_space(3))) void*)((char*)Bs + lbase), 16, 0, 0);
    }
    __syncthreads();
#pragma unroll
    for (int kc = 0; kc < 2; ++kc) {
      half8 af[4], bf[4];
#pragma unroll
      for (int i = 0; i < 4; ++i) {
        af[i] = *(const half8*)(As + (wm * 64 + i * 16 + c) * 64 + kc * 32 + q * 8);
        bf[i] = *(const half8*)(Bs + (wn * 64 + i * 16 + c) * 64 + kc * 32 + q * 8);
      }
#pragma unroll
      for (int i = 0; i < 4; ++i)
#pragma unroll
        for (int j = 0; j < 4; ++j)
          acc[i][j] = __builtin_amdgcn_mfma_f32_16x16x32_f16(af[i], bf[j], acc[i][j], 0, 0, 0);
    }
  }

  // Epilogue: per output row, blockmax over this wave's 64 cols + argcol.
  // C/D layout: col = lane&15 (c), row = q*4 + reg.
  const int colhalf = blockIdx.y * 2 + wn;        // 64-col block index in [0, NB_)
#pragma unroll
  for (int i = 0; i < 4; ++i)
#pragma unroll
    for (int r = 0; r < 4; ++r) {
      float rm = acc[i][3][r]; int jb = 3;
#pragma unroll
      for (int j = 2; j >= 0; --j)                 // >= : lowest j wins ties
        if (acc[i][j][r] >= rm) { rm = acc[i][j][r]; jb = j; }
      const unsigned rel = (unsigned)(jb * 16 + c);
      unsigned long long best =
          ((unsigned long long)mono(rm) << 32) | (unsigned long long)(63u - rel);
#pragma unroll
      for (int off = 1; off < 16; off <<= 1) {     // 16 lanes share this row
        const unsigned long long o = __shfl_xor(best, off, 64);
        best = best > o ? best : o;
      }
      if (c == 0) {
        const int mrow = m0 + wm * 64 + i * 16 + q * 4 + r;
        bm[(long)mrow * NB_ + colhalf] = best;
      }
    }
}

// ---------------------------------------------------------------------------
// Phase 2: per row, reduce 1024 block-maxima; fp32-rescore block-argmax cols
// within MARGIN of the approx row max; numpy tie-break (lowest col).
// One wave per row. No atomics; robust to any candidate count.
// ---------------------------------------------------------------------------
__global__ __launch_bounds__(256) void bikv_argmax(
    const unsigned long long* __restrict__ bm,
    const float* __restrict__ idxb, const float* __restrict__ tab,
    int* __restrict__ ch)
{
  const int t = threadIdx.x, wv = t >> 6, l = t & 63;
  const int row = blockIdx.x * 4 + wv;
  const unsigned long long* prow = bm + (long)row * NB_;
  unsigned long long p[16];
#pragma unroll
  for (int s = 0; s < 16; ++s) p[s] = prow[s * 64 + l];
  unsigned long long best = 0ull;
#pragma unroll
  for (int s = 0; s < 16; ++s) best = best > p[s] ? best : p[s];
#pragma unroll
  for (int off = 1; off < 64; off <<= 1) {
    const unsigned long long o = __shfl_xor(best, off, 64);
    best = best > o ? best : o;
  }
  const float rmax = unmono((unsigned)(best >> 32));
  const unsigned thrm = mono(rmax - MARGIN);

  const float* arow = idxb + (long)row * I_ + l * 8;
  float a[8];
#pragma unroll
  for (int j = 0; j < 8; ++j) a[j] = arow[j];

  unsigned long long bestE = 0ull;
#pragma unroll
  for (int s = 0; s < 16; ++s) {
    unsigned long long mask = __ballot((unsigned)(p[s] >> 32) > thrm);
    while (mask) {
      const int ln = __ffsll((unsigned long long)mask) - 1;
      mask &= mask - 1;
      const unsigned long long pk = __shfl(p[s], ln, 64);
      const int blk = s * 64 + ln;
      const int rel = 63 - (int)(unsigned)(pk & 0xFFFFFFFFull);
      const int col = blk * 64 + rel;
      const float* tr = tab + (long)col * I_ + l * 8;
      float sdot = 0.f;
#pragma unroll
      for (int j = 0; j < 8; ++j) sdot = fmaf(a[j], tr[j], sdot);
#pragma unroll
      for (int off = 32; off >= 1; off >>= 1) sdot += __shfl_xor(sdot, off, 64);
      const unsigned long long pe =
          ((unsigned long long)mono(sdot) << 32) |
          (unsigned long long)(0xFFFFFFFFu - (unsigned)col);
      bestE = bestE > pe ? bestE : pe;
    }
  }
  if (l == 0) ch[row] = (int)(0xFFFFFFFFu - (unsigned)(bestE & 0xFFFFFFFFull));
}

// ---------------------------------------------------------------------------
// Gather chosen rows of keys_tab/values_tab -> f16
// ---------------------------------------------------------------------------
__global__ __launch_bounds__(256) void bikv_gather_kv(
    const int* __restrict__ ch, const float* __restrict__ ktab,
    const float* __restrict__ vtab, _Float16* __restrict__ ck,
    _Float16* __restrict__ cv)
{
  const int i = blockIdx.x * 256 + threadIdx.x;   // i < M_*64
  const int m = i >> 6, c8 = (i & 63) * 8;
  const long src = (long)ch[m] * H_ + c8;
  const long dst = (long)m * H_ + c8;
  {
    const float4 a = *(const float4*)(ktab + src);
    const float4 b = *(const float4*)(ktab + src + 4);
    half8 o;
    o[0]=(_Float16)a.x; o[1]=(_Float16)a.y; o[2]=(_Float16)a.z; o[3]=(_Float16)a.w;
    o[4]=(_Float16)b.x; o[5]=(_Float16)b.y; o[6]=(_Float16)b.z; o[7]=(_Float16)b.w;
    *(half8*)(ck + dst) = o;
  }
  {
    const float4 a = *(const float4*)(vtab + src);
    const float4 b = *(const float4*)(vtab + src + 4);
    half8 o;
    o[0]=(_Float16)a.x; o[1]=(_Float16)a.y; o[2]=(_Float16)a.z; o[3]=(_Float16)a.w;
    o[4]=(_Float16)b.x; o[5]=(_Float16)b.y; o[6]=(_Float16)b.z; o[7]=(_Float16)b.w;
    *(half8*)(cv + dst) = o;
  }
}

// ---------------------------------------------------------------------------
// f16 MFMA GEMM, B-transposed. 64x64 tile, 4 waves (2x2 of 32x32).
// Optional sigmoid / gather / bias-vec / f32 / f16 outputs.
// ---------------------------------------------------------------------------
template<bool SIG, bool GATH, bool BVEC, bool WF32, bool WF16>
__global__ __launch_bounds__(256) void bikv_gemm_h(
    const _Float16* __restrict__ A, const _Float16* __restrict__ W,
    float* __restrict__ C, _Float16* __restrict__ C16,
    const int* __restrict__ gidx, const float* __restrict__ bvec,
    int N, int Kd, long sA, long sW, long sC)
{
  A += (long)blockIdx.z * sA;
  W += (long)blockIdx.z * sW;
  if (WF32) C += (long)blockIdx.z * sC;
  if (WF16) C16 += (long)blockIdx.z * sC;
  __shared__ _Float16 As[64 * 32];
  __shared__ _Float16 Ws[64 * 32];
  const int t = threadIdx.x;
  const int w = t >> 6, l = t & 63;
  const int q = l >> 4, c = l & 15;
  const int wm = w >> 1, wn = w & 1;
  const int m0 = blockIdx.x * 64;
  const int n0 = blockIdx.y * 64;
  const int srow = t >> 2, schunk = t & 3;
  const long abase = (long)(GATH ? gidx[m0 + srow] : (m0 + srow)) * Kd;
  const long wbase = (long)(n0 + srow) * Kd;
  const int lbase = w * 1024;

  f32x4 acc[2][2];
#pragma unroll
  for (int i = 0; i < 2; ++i)
#pragma unroll
    for (int j = 0; j < 2; ++j) acc[i][j] = (f32x4)0.0f;

  for (int kk = 0; kk < Kd; kk += 32) {
    __syncthreads();
    __builtin_amdgcn_global_load_lds(
        (const __attribute__((address_space(1))) void*)(A + abase + kk + schunk * 8),
        (__attribute__((address_space(3))) void*)((char*)As + lbase), 16, 0, 0);
    __builtin_amdgcn_global_load_lds(
        (const __attribute__((address_space(1))) void*)(W + wbase + kk + schunk * 8),
        (__attribute__((address_space(3))) void*)((char*)Ws + lbase), 16, 0, 0);
    __syncthreads();
    half8 af[2], bf[2];
#pragma unroll
    for (int i = 0; i < 2; ++i) {
      af[i] = *(const half8*)(As + (wm * 32 + i * 16 + c) * 32 + q * 8);
      bf[i] = *(const half8*)(Ws + (wn * 32 + i * 16 + c) * 32 + q * 8);
    }
#pragma unroll
    for (int i = 0; i < 2; ++i)
#pragma unroll
      for (int j = 0; j < 2; ++j)
        acc[i][j] = __builtin_amdgcn_mfma_f32_16x16x32_f16(af[i], bf[j], acc[i][j], 0, 0, 0);
  }
#pragma unroll
  for (int i = 0; i < 2; ++i)
#pragma unroll
    for (int r = 0; r < 4; ++r) {
      const long m = m0 + wm * 32 + i * 16 + q * 4 + r;
#pragma unroll
      for (int j = 0; j < 2; ++j) {
        const int n = n0 + wn * 32 + j * 16 + c;
        float v = acc[i][j][r];
        if (BVEC) v += bvec[n];
        if (SIG)  v = 1.0f / (1.0f + expf(-v));
        if (WF32) C[m * N + n] = v;
        if (WF16) C16[m * N + n] = (_Float16)v;
      }
    }
}

// ---------------------------------------------------------------------------
// Batched q/k/v projection: z selects (A, W, C) triple. Same tile as above.
// ---------------------------------------------------------------------------
__global__ __launch_bounds__(256) void bikv_gemm_qkv3(
    const _Float16* __restrict__ A0, const _Float16* __restrict__ A1,
    const _Float16* __restrict__ A2,
    const _Float16* __restrict__ W0, const _Float16* __restrict__ W1,
    const _Float16* __restrict__ W2,
    float* __restrict__ C0, float* __restrict__ C1, float* __restrict__ C2)
{
  const int z = blockIdx.z;
  const _Float16* A = (z == 0) ? A0 : (z == 1) ? A1 : A2;
  const _Float16* W = (z == 0) ? W0 : (z == 1) ? W1 : W2;
  float* C = (z == 0) ? C0 : (z == 1) ? C1 : C2;
  __shared__ _Float16 As[64 * 32];
  __shared__ _Float16 Ws[64 * 32];
  const int t = threadIdx.x;
  const int w = t >> 6, l = t & 63;
  const int q = l >> 4, c = l & 15;
  const int wm = w >> 1, wn = w & 1;
  const int m0 = blockIdx.x * 64;
  const int n0 = blockIdx.y * 64;
  const int srow = t >> 2, schunk = t & 3;
  const long abase = (long)(m0 + srow) * H_;
  const long wbase = (long)(n0 + srow) * H_;
  const int lbase = w * 1024;

  f32x4 acc[2][2];
#pragma unroll
  for (int i = 0; i < 2; ++i)
#pragma unroll
    for (int j = 0; j < 2; ++j) acc[i][j] = (f32x4)0.0f;

  for (int kk = 0; kk < H_; kk += 32) {
    __syncthreads();
    __builtin_amdgcn_global_load_lds(
        (const __attribute__((address_space(1))) void*)(A + abase + kk + schunk * 8),
        (__attribute__((address_space(3))) void*)((char*)As + lbase), 16, 0, 0);
    __builtin_amdgcn_global_load_lds(
        (const __attribute__((address_space(1))) void*)(W + wbase + kk + schunk * 8),
        (__attribute__((address_space(3))) void*)((char*)Ws + lbase), 16, 0, 0);
    __syncthreads();
    half8 af[2], bf[2];
#pragma unroll
    for (int i = 0; i < 2; ++i) {
      af[i] = *(const half8*)(As + (wm * 32 + i * 16 + c) * 32 + q * 8);
      bf[i] = *(const half8*)(Ws + (wn * 32 + i * 16 + c) * 32 + q * 8);
    }
#pragma unroll
    for (int i = 0; i < 2; ++i)
#pragma unroll
      for (int j = 0; j < 2; ++j)
        acc[i][j] = __builtin_amdgcn_mfma_f32_16x16x32_f16(af[i], bf[j], acc[i][j], 0, 0, 0);
  }
#pragma unroll
  for (int i = 0; i < 2; ++i)
#pragma unroll
    for (int r = 0; r < 4; ++r) {
      const long m = m0 + wm * 32 + i * 16 + q * 4 + r;
#pragma unroll
      for (int j = 0; j < 2; ++j) {
        const int n = n0 + wn * 32 + j * 16 + c;
        C[m * H_ + n] = acc[i][j][r];
      }
    }
}

// ---------------------------------------------------------------------------
// Rotary for q AND k in one dispatch (cos/sin indexed by HEAD index — quirk)
// ---------------------------------------------------------------------------
__global__ __launch_bounds__(256) void bikv_rotary2(
    float* __restrict__ qb, float* __restrict__ kb)
{
  int e = blockIdx.x * 256 + threadIdx.x;          // < 2 * M_*NH_*32
  float* buf = (e < M_ * NH_ * 32) ? qb : kb;
  e &= (M_ * NH_ * 32 - 1);
  const int j  = e & 31;
  const int nh = (e >> 5) & 7;
  const long m = e >> 8;
  const float inv = expf(-(float)j * (9.2103403719761836f / 32.0f));
  const float arg = (float)nh * inv;
  const float c = cosf(arg), s = sinf(arg);
  float* p = buf + m * H_ + nh * HD_ + j;
  const float x1 = p[0], x2 = p[32];
  p[0]  = x1 * c - x2 * s;
  p[32] = x2 * c + x1 * s;
}

// ---------------------------------------------------------------------------
// Flash attention, one wave per query. K row-major, V transposed in LDS.
// ---------------------------------------------------------------------------
__global__ __launch_bounds__(256) void bikv_attn(
    const float* __restrict__ qb, const float* __restrict__ kb,
    const float* __restrict__ vb, const float* __restrict__ bias,
    _Float16* __restrict__ o16)
{
  const int b = blockIdx.z, h = blockIdx.y;
  const int t = threadIdx.x, wv = t >> 6, lane = t & 63;
  const int q = blockIdx.x * 4 + wv;
  __shared__ float kt[64][68];
  __shared__ float vt[64][68];
  __shared__ float qs[4][64];
  __shared__ float wsh[4][64];
  const long qoff = (((long)(b * S_ + q)) * NH_ + h) * HD_;
  qs[wv][lane] = qb[qoff + lane];
  const float* biasrow = bias + ((long)b * S_ + q) * S_;
  const int ntiles = (blockIdx.x >> 4) + 1;
  float m = -INFINITY, l = 0.f, oacc = 0.f;
  for (int tau = 0; tau < ntiles; ++tau) {
    const int t0 = tau * 64;
    __syncthreads();
    {
      const float* ksrc = kb + (((long)(b * S_ + t0)) * NH_ + h) * HD_;
      const float* vsrc = vb + (((long)(b * S_ + t0)) * NH_ + h) * HD_;
      int l4 = t;
#pragma unroll
      for (int rep = 0; rep < 4; ++rep, l4 += 256) {
        const int row = l4 >> 4;
        const int c4  = (l4 & 15) << 2;
        const float4 k4 = *(const float4*)(ksrc + (long)row * (NH_*HD_) + c4);
        const float4 v4 = *(const float4*)(vsrc + (long)row * (NH_*HD_) + c4);
        *(float4*)&kt[row][c4] = k4;
        vt[c4+0][row] = v4.x; vt[c4+1][row] = v4.y;
        vt[c4+2][row] = v4.z; vt[c4+3][row] = v4.w;
      }
    }
    __syncthreads();
    const int tg = t0 + lane;
    const bool valid = tg <= q;
    float dot = 0.f;
#pragma unroll
    for (int d0 = 0; d0 < 16; ++d0) {
      const float4 k4 = *(const float4*)&kt[lane][d0 * 4];
      const float4 q4 = *(const float4*)&qs[wv][d0 * 4];
      dot = fmaf(k4.x, q4.x, dot); dot = fmaf(k4.y, q4.y, dot);
      dot = fmaf(k4.z, q4.z, dot); dot = fmaf(k4.w, q4.w, dot);
    }
    const float sc = valid ? (dot * 0.125f + biasrow[tg]) : -INFINITY;
    float tm = sc;
#pragma unroll
    for (int off = 32; off >= 1; off >>= 1) tm = fmaxf(tm, __shfl_xor(tm, off, 64));
    const float mnew  = fmaxf(m, tm);
    const float alpha = expf(m - mnew);
    const float wgt = valid ? expf(sc - mnew) : 0.f;
    float sw = wgt;
#pragma unroll
    for (int off = 32; off >= 1; off >>= 1) sw += __shfl_xor(sw, off, 64);
    l = l * alpha + sw;
    wsh[wv][lane] = wgt;
    float pa = 0.f;
#pragma unroll
    for (int tt0 = 0; tt0 < 16; ++tt0) {
      const float4 v4 = *(const float4*)&vt[lane][tt0 * 4];
      const float4 w4 = *(const float4*)&wsh[wv][tt0 * 4];
      pa = fmaf(v4.x, w4.x, pa); pa = fmaf(v4.y, w4.y, pa);
      pa = fmaf(v4.z, w4.z, pa); pa = fmaf(v4.w, w4.w, pa);
    }
    oacc = oacc * alpha + pa;
    m = mnew;
  }
  o16[qoff + lane] = (_Float16)(oacc / l);
}

// ---------------------------------------------------------------------------
extern "C" void kernel_launch(void* const* d_in, const int* in_sizes, int n_in,
                              void* d_out, int out_size, void* d_ws, size_t ws_size,
                              hipStream_t stream)
{
  const float* X     = (const float*)d_in[0];
  const float* i_w   = (const float*)d_in[1];
  const float* q_w   = (const float*)d_in[2];
  const float* k_w   = (const float*)d_in[3];
  const float* v_w   = (const float*)d_in[4];
  const float* out_w = (const float*)d_in[5];
  const float* out_b = (const float*)d_in[6];
  const float* tab   = (const float*)d_in[7];
  const float* ktab  = (const float*)d_in[8];
  const float* vtab  = (const float*)d_in[9];
  float* out = (float*)d_out;

  char* ws = (char*)d_ws;
  size_t off = 0;
  auto alloc = [&](size_t bytes) -> void* {
    void* p = ws + off; off += (bytes + 255) & ~(size_t)255; return p;
  };
  auto choices = (int*)alloc(M_ * 4);
  auto idxb    = (float*)alloc((size_t)M_ * I_ * 4);
  auto qbuf    = (float*)alloc((size_t)M_ * H_ * 4);
  auto kbuf    = (float*)alloc((size_t)M_ * H_ * 4);
  auto vbuf    = (float*)alloc((size_t)M_ * H_ * 4);
  auto biasb   = (float*)alloc((size_t)B_ * S_ * S_ * 4);
  auto idx16   = (_Float16*)alloc((size_t)M_ * I_ * 2);
  auto chosen16= (_Float16*)alloc((size_t)M_ * I_ * 2);
  auto X16     = (_Float16*)alloc((size_t)M_ * H_ * 2);
  auto iw16    = (_Float16*)alloc((size_t)H_ * H_ * 2);
  auto qw16    = (_Float16*)alloc((size_t)H_ * H_ * 2);
  auto kw16    = (_Float16*)alloc((size_t)H_ * H_ * 2);
  auto vw16    = (_Float16*)alloc((size_t)H_ * H_ * 2);
  auto ow16    = (_Float16*)alloc((size_t)H_ * H_ * 2);
  auto ck16    = (_Float16*)alloc((size_t)M_ * H_ * 2);
  auto cv16    = (_Float16*)alloc((size_t)M_ * H_ * 2);
  auto o16     = (_Float16*)alloc((size_t)M_ * H_ * 2);
  auto tab16   = (_Float16*)alloc((size_t)K_ * I_ * 2);          // 67 MB
  auto bm      = (unsigned long long*)alloc((size_t)M_ * NB_ * 8); // 16.8 MB

  // conversions (tab big; X + 5 weights fused)
  bikv_f2h<<<(K_*I_/8)/256, 256, 0, stream>>>(tab, tab16, K_*I_/8);
  bikv_f2h_multi<<<1152, 256, 0, stream>>>(X, X16, i_w, iw16, q_w, qw16,
                                           k_w, kw16, v_w, vw16, out_w, ow16);

  // idx = sigmoid(X . i_w^T) — fp32 + fused f16 copy
  bikv_gemm_f32_sig<<<dim3(M_/64, I_/64), 256, 0, stream>>>(
      X, i_w, idxb, idx16, I_, H_);

  // Phase 1: MFMA sim -> per-(row, 64-block) argmax table (no atomics)
  bikv_sim_bm<<<dim3(M_/128, K_/128), 256, 0, stream>>>(idx16, tab16, bm);
  // Phase 2: row reduce + exact fp32 rescore of margin blocks
  bikv_argmax<<<M_/4, 256, 0, stream>>>(bm, idxb, tab, choices);

  // gather chosen k/v rows -> f16
  bikv_gather_kv<<<(M_*64)/256, 256, 0, stream>>>(choices, ktab, vtab, ck16, cv16);

  // chosen = sigmoid(tab[choices] . i_w^T) — f16 out only (feeds bias GEMM)
  bikv_gemm_h<true,true,false,false,true><<<dim3(M_/64, I_/64), 256, 0, stream>>>(
      tab16, iw16, nullptr, chosen16, choices, nullptr, I_, I_, 0, 0, 0);

  // q/k/v projections, one dispatch
  bikv_gemm_qkv3<<<dim3(M_/64, H_/64, 3), 256, 0, stream>>>(
      X16, ck16, cv16, qw16, kw16, vw16, qbuf, kbuf, vbuf);

  bikv_rotary2<<<(2*M_*NH_*32)/256, 256, 0, stream>>>(qbuf, kbuf);

  // bias[b,s,t] = idx[b,s,:] . chosen[b,t,:]
  bikv_gemm_h<false,false,false,true,false><<<dim3(S_/64, S_/64, B_), 256, 0, stream>>>(
      idx16, chosen16, biasb, nullptr, nullptr, nullptr, S_, I_,
      (long)S_ * I_, (long)S_ * I_, (long)S_ * S_);

  bikv_attn<<<dim3(S_/4, NH_, B_), 256, 0, stream>>>(qbuf, kbuf, vbuf, biasb, o16);

  // out = o . out_w^T + out_b
  bikv_gemm_h<false,false,true,true,false><<<dim3(M_/64, H_/64), 256, 0, stream>>>(
      o16, ow16, out, nullptr, nullptr, out_b, H_, H_, 0, 0, 0);
}